// Round 3
// baseline (271.538 us; speedup 1.0000x reference)
//
#include <hip/hip_runtime.h>
#include <hip/hip_bf16.h>

#define BS 32768
#define NWP 10
#define DD 256
#define NEXP 6
#define HH 64
#define OUT_DIM 2
#define MB 32   // batch items per gemm block

typedef short bf16x8 __attribute__((ext_vector_type(8)));
typedef float f32x4 __attribute__((ext_vector_type(4)));

__device__ inline short bfs(float f) {
  __hip_bfloat16 h = __float2bfloat16(f);   // RNE; compiler pairs into v_cvt_pk_bf16_f32
  return __builtin_bit_cast(short, h);
}

// ---------------- kernel 1: bucket batch indices by expert ----------------
__global__ void bucket_k(const int* __restrict__ cmd,
                         int* __restrict__ counts,
                         unsigned short* __restrict__ lists) {
  const int b = blockIdx.x * 256 + threadIdx.x;   // grid covers exactly BS
  const int e = cmd[b];
  const int lane = threadIdx.x & 63;
  #pragma unroll
  for (int ee = 0; ee < NEXP; ++ee) {
    unsigned long long m = __ballot(e == ee);
    if (e == ee) {
      const int leader = __ffsll((long long)m) - 1;
      const int nbelow = __popcll(m & ((1ull << lane) - 1ull));
      int base = 0;
      if (lane == leader) base = atomicAdd(&counts[ee], __popcll(m));
      base = __shfl(base, leader);   // leader active in this branch -> defined
      lists[ee * BS + base + nbelow] = (unsigned short)b;
    }
  }
}

// ---------------- kernel 1b: W1 -> W1T bf16 [e][h][d] ----------------
__global__ void prep_w1t_k(const float* __restrict__ W1, short* __restrict__ W1T) {
  const int e = blockIdx.x;
  const int h = threadIdx.x & 63;
  const int dq = threadIdx.x >> 6;                  // 0..3
  const float* wp = W1 + (size_t)e * DD * HH + h;   // stride HH over d
  short* op = W1T + (size_t)e * HH * DD + (size_t)h * DD;
  #pragma unroll
  for (int j = 0; j < 8; ++j) {
    const int d0 = dq * 64 + j * 8;
    bf16x8 v;
    #pragma unroll
    for (int i = 0; i < 8; ++i) v[i] = bfs(wp[(size_t)(d0 + i) * HH]);
    *(bf16x8*)(op + d0) = v;
  }
}

// ---------------- kernel 2: LDS-free fused GEMM + cumsum ----------------
__global__ __launch_bounds__(256, 4) void moe_gemm_k(
    const float* __restrict__ x,
    const float* __restrict__ re,
    const float* __restrict__ b1,
    const float* __restrict__ W2,
    const float* __restrict__ b2,
    const int* __restrict__ counts,
    const unsigned short* __restrict__ lists,
    const short* __restrict__ W1T,    // [6][64][256] bf16
    float* __restrict__ out)
{
  __shared__ float po[MB * NWP * 2];  // 2.5 KB: pre-cumsum per-row outputs

  const int e = blockIdx.y;
  const int cnt = counts[e];
  const int start = blockIdx.x * MB;
  if (start >= cnt) return;
  const int nb = min(MB, cnt - start);
  const int nrows = nb * NWP;

  const int tid = threadIdx.x;
  const int lane = tid & 63;
  const int wv = tid >> 6;
  const int arow = lane & 15;
  const int ag = lane >> 4;

  int bid_reg = 0;
  if (lane < nb) bid_reg = (int)lists[e * BS + start + lane];

  // hoisted per-lane epilogue weights (depend on e, nt, arow only)
  float b1v[4], w20[4], w21[4];
  #pragma unroll
  for (int nt = 0; nt < 4; ++nt) {
    const int col = nt * 16 + arow;
    b1v[nt] = b1[e * HH + col];
    w20[nt] = W2[((size_t)e * HH + col) * OUT_DIM + 0];
    w21[nt] = W2[((size_t)e * HH + col) * OUT_DIM + 1];
  }
  const float bb0 = b2[e * OUT_DIM + 0];
  const float bb1 = b2[e * OUT_DIM + 1];

  const short* Wt = W1T + (size_t)e * HH * DD + arow * DD + ag * 8;

  const int ntile = (nrows + 15) >> 4;
  for (int c = wv; c < ntile; c += 4) {
    const int r0 = c * 16;
    const int rowc = min(r0 + arow, nrows - 1);
    const int bi = rowc / 10;
    const int n = rowc - bi * 10;
    const int gb = __shfl(bid_reg, bi);            // all 64 lanes active
    const float* xb = x + ((size_t)gb * NWP + n) * DD + ag * 8;
    const float* rb = re + (size_t)n * DD + ag * 8;

    f32x4 acc[4] = {{0,0,0,0},{0,0,0,0},{0,0,0,0},{0,0,0,0}};
    #pragma unroll
    for (int ks = 0; ks < 8; ++ks) {
      const float4 xa = *(const float4*)(xb + ks * 32);
      const float4 xc = *(const float4*)(xb + ks * 32 + 4);
      const float4 ra = *(const float4*)(rb + ks * 32);
      const float4 rc = *(const float4*)(rb + ks * 32 + 4);
      bf16x8 a;
      a[0] = bfs(xa.x + ra.x); a[1] = bfs(xa.y + ra.y);
      a[2] = bfs(xa.z + ra.z); a[3] = bfs(xa.w + ra.w);
      a[4] = bfs(xc.x + rc.x); a[5] = bfs(xc.y + rc.y);
      a[6] = bfs(xc.z + rc.z); a[7] = bfs(xc.w + rc.w);
      const short* wb = Wt + ks * 32;
      #pragma unroll
      for (int nt = 0; nt < 4; ++nt) {
        const bf16x8 bv = *(const bf16x8*)(wb + nt * 16 * DD);
        acc[nt] = __builtin_amdgcn_mfma_f32_16x16x32_bf16(a, bv, acc[nt], 0, 0, 0);
      }
    }

    // epilogue: relu(acc + b1) @ W2, reduce over the 16 h-lanes
    float p0[4] = {0,0,0,0}, p1[4] = {0,0,0,0};
    #pragma unroll
    for (int nt = 0; nt < 4; ++nt) {
      #pragma unroll
      for (int rg = 0; rg < 4; ++rg) {
        const float hv = fmaxf(acc[nt][rg] + b1v[nt], 0.0f);
        p0[rg] += hv * w20[nt];
        p1[rg] += hv * w21[nt];
      }
    }
    #pragma unroll
    for (int off = 1; off < 16; off <<= 1) {
      #pragma unroll
      for (int rg = 0; rg < 4; ++rg) {
        p0[rg] += __shfl_xor(p0[rg], off);
        p1[rg] += __shfl_xor(p1[rg], off);
      }
    }
    if (arow == 0) {
      #pragma unroll
      for (int rg = 0; rg < 4; ++rg) {
        const int row = r0 + ag * 4 + rg;
        if (row < nrows) {
          po[row * 2 + 0] = p0[rg] + bb0;
          po[row * 2 + 1] = p1[rg] + bb1;
        }
      }
    }
  }

  __syncthreads();

  // fused cumsum + writeout: one thread per batch item
  if (tid < nb) {
    const int gb = (int)lists[e * BS + start + tid];
    float v[NWP * 2];
    float s0 = 0.f, s1 = 0.f;
    #pragma unroll
    for (int n = 0; n < NWP; ++n) {
      s0 += po[(tid * NWP + n) * 2 + 0];
      s1 += po[(tid * NWP + n) * 2 + 1];
      v[n * 2] = s0; v[n * 2 + 1] = s1;
    }
    float4* op = (float4*)(out + (size_t)gb * NWP * OUT_DIM);  // 80B, 16B-aligned
    #pragma unroll
    for (int q = 0; q < 5; ++q)
      op[q] = make_float4(v[q * 4], v[q * 4 + 1], v[q * 4 + 2], v[q * 4 + 3]);
  }
}

extern "C" void kernel_launch(void* const* d_in, const int* in_sizes, int n_in,
                              void* d_out, int out_size, void* d_ws, size_t ws_size,
                              hipStream_t stream) {
  const float* x          = (const float*)d_in[0];
  const int*   meas       = (const int*)d_in[1];
  const float* rank_embed = (const float*)d_in[2];
  const float* W1         = (const float*)d_in[3];
  const float* b1         = (const float*)d_in[4];
  const float* W2         = (const float*)d_in[5];
  const float* b2         = (const float*)d_in[6];
  float* out = (float*)d_out;

  int* counts = (int*)d_ws;                                      // 6 ints
  unsigned short* lists = (unsigned short*)((char*)d_ws + 256);  // 6*BS ushort
  short* W1T = (short*)((char*)d_ws + (512 << 10));              // 192 KB bf16

  hipMemsetAsync(d_ws, 0, 256, stream);
  bucket_k<<<BS / 256, 256, 0, stream>>>(meas, counts, lists);
  prep_w1t_k<<<NEXP, 256, 0, stream>>>(W1, W1T);
  dim3 gg((BS + MB - 1) / MB, NEXP);
  moe_gemm_k<<<gg, 256, 0, stream>>>(x, rank_embed, b1, W2, b2,
                                     counts, lists, W1T, out);
}

// Round 4
// 184.700 us; speedup vs baseline: 1.4702x; 1.4702x over previous
//
#include <hip/hip_runtime.h>
#include <hip/hip_bf16.h>

#define BS 32768
#define NWP 10
#define DD 256
#define NEXP 6
#define HH 64
#define OUT_DIM 2
#define MB 32
#define TROWS 16
#define NTILE ((MB * NWP) / TROWS)   // 20

typedef short bf16x8 __attribute__((ext_vector_type(8)));
typedef float f32x4 __attribute__((ext_vector_type(4)));

__device__ inline short bfs(float f) {
  __hip_bfloat16 h = __float2bfloat16(f);   // RNE
  return __builtin_bit_cast(short, h);
}

// global -> LDS direct DMA, 16B per lane. Dest is wave-uniform base (+lane*16 in HW),
// source is per-lane (carries the swizzle).
__device__ inline void gload_lds16(const float* g, float* l) {
  __builtin_amdgcn_global_load_lds(
      (const __attribute__((address_space(1))) void*)g,
      (__attribute__((address_space(3))) void*)l, 16, 0, 0);
}

// ---------------- kernel 1: bucket batch indices by expert ----------------
__global__ void bucket_k(const int* __restrict__ cmd,
                         int* __restrict__ counts,
                         unsigned short* __restrict__ lists) {
  const int b = blockIdx.x * 256 + threadIdx.x;
  const int e = cmd[b];
  const int lane = threadIdx.x & 63;
  #pragma unroll
  for (int ee = 0; ee < NEXP; ++ee) {
    unsigned long long m = __ballot(e == ee);
    if (e == ee) {
      const int leader = __ffsll((long long)m) - 1;
      const int nbelow = __popcll(m & ((1ull << lane) - 1ull));
      int base = 0;
      if (lane == leader) base = atomicAdd(&counts[ee], __popcll(m));
      base = __shfl(base, leader);
      lists[ee * BS + base + nbelow] = (unsigned short)b;
    }
  }
}

// ---------------- kernel 2: pipelined fused GEMM + cumsum ----------------
__global__ __launch_bounds__(256, 3) void moe_gemm_k(
    const float* __restrict__ x,
    const float* __restrict__ re,
    const float* __restrict__ W1,
    const float* __restrict__ b1,
    const float* __restrict__ W2,
    const float* __restrict__ b2,
    const int* __restrict__ counts,
    const unsigned short* __restrict__ lists,
    float* __restrict__ out)
{
  __shared__ float Xt[2][TROWS][DD];   // 32 KB double-buffered x tile (fp32, swizzled)
  __shared__ float Re[NWP][DD];        // 10 KB rank_embed (fp32, swizzled)
  __shared__ float po[MB * NWP][2];    // 2.5 KB pre-cumsum outputs

  const int e = blockIdx.y;
  const int cnt = counts[e];
  const int start = blockIdx.x * MB;
  if (start >= cnt) return;
  const int nb = min(MB, cnt - start);
  const int nrows = nb * NWP;

  const int tid = threadIdx.x;
  const int lane = tid & 63;
  const int wv = tid >> 6;
  const int arow = lane & 15;
  const int ag = lane >> 4;

  int bid_reg = 0;
  if (lane < nb) bid_reg = (int)lists[e * BS + start + lane];

  // init po to b2 (each row gets bias exactly once)
  const float bb0 = b2[e * OUT_DIM + 0];
  const float bb1 = b2[e * OUT_DIM + 1];
  for (int i = tid; i < MB * NWP; i += 256) { po[i][0] = bb0; po[i][1] = bb1; }

  // B fragments in registers: wave wv owns output cols hcol = wv*16 + arow
  const int hcol = wv * 16 + arow;
  bf16x8 Bf[8];
  {
    const float* wp = W1 + (size_t)e * DD * HH + hcol;
    #pragma unroll
    for (int ks = 0; ks < 8; ++ks) {
      #pragma unroll
      for (int j = 0; j < 8; ++j)
        Bf[ks][j] = bfs(wp[(size_t)(ks * 32 + ag * 8 + j) * HH]);
    }
  }
  const float b1v = b1[e * HH + hcol];
  const float w20 = W2[((size_t)e * HH + hcol) * OUT_DIM + 0];
  const float w21 = W2[((size_t)e * HH + hcol) * OUT_DIM + 1];

  // stage rank_embed once (linear LDS dest, inverse-swizzled global source)
  if (wv == 0) {
    #pragma unroll
    for (int n = 0; n < NWP; ++n)
      gload_lds16(re + (size_t)n * DD + (((lane * 16) ^ ((n & 7) << 4)) >> 2),
                  &Re[n][0]);
  }

  __syncthreads();   // full drain: vmcnt==0 on every wave at loop entry

  // stage 4 rows of tile t into buf (1 KB per gload_lds == one full row)
  auto stage = [&](int t, int buf) {
    #pragma unroll
    for (int r = 0; r < 4; ++r) {
      const int rl = wv * 4 + r;
      const int rowc = min(t * TROWS + rl, nrows - 1);
      const int bi = rowc / NWP;
      const int n = rowc - bi * NWP;
      const int gb = __shfl(bid_reg, bi);   // uniform index, all lanes active
      const float* src = x + ((size_t)gb * NWP + n) * DD
                       + (((lane * 16) ^ ((rl & 7) << 4)) >> 2);
      gload_lds16(src, &Xt[buf][rl][0]);
    }
  };

  stage(0, 0);

  for (int t = 0; t < NTILE; ++t) {
    const int cur = t & 1;
    stage(min(t + 1, NTILE - 1), cur ^ 1);          // prefetch next tile
    asm volatile("s_waitcnt vmcnt(4)" ::: "memory"); // tile t's 4 rows landed (mine)
    __builtin_amdgcn_s_barrier();                    // everyone's rows landed
    __builtin_amdgcn_sched_barrier(0);

    const int rowc = min(t * TROWS + arow, nrows - 1);
    const int nn = rowc - (rowc / NWP) * NWP;
    const int key = (arow & 7) << 4;
    const int nkey = (nn & 7) << 4;
    const char* xrow = (const char*)&Xt[cur][arow][0];
    const char* rrow = (const char*)&Re[nn][0];

    f32x4 acc = {0.f, 0.f, 0.f, 0.f};
    #pragma unroll
    for (int ks = 0; ks < 8; ++ks) {
      const int b0 = ks * 128 + ag * 32;
      const float4 xa = *(const float4*)(xrow + ((b0) ^ key));
      const float4 xc = *(const float4*)(xrow + ((b0 + 16) ^ key));
      const float4 ra = *(const float4*)(rrow + ((b0) ^ nkey));
      const float4 rc = *(const float4*)(rrow + ((b0 + 16) ^ nkey));
      bf16x8 a;
      a[0] = bfs(xa.x + ra.x); a[1] = bfs(xa.y + ra.y);
      a[2] = bfs(xa.z + ra.z); a[3] = bfs(xa.w + ra.w);
      a[4] = bfs(xc.x + rc.x); a[5] = bfs(xc.y + rc.y);
      a[6] = bfs(xc.z + rc.z); a[7] = bfs(xc.w + rc.w);
      acc = __builtin_amdgcn_mfma_f32_16x16x32_bf16(a, Bf[ks], acc, 0, 0, 0);
    }

    // epilogue: relu(+b1) @ W2 partial over this wave's 16 cols
    float p0[4], p1[4];
    #pragma unroll
    for (int rg = 0; rg < 4; ++rg) {
      const float hv = fmaxf(acc[rg] + b1v, 0.f);
      p0[rg] = hv * w20;
      p1[rg] = hv * w21;
    }
    #pragma unroll
    for (int off = 1; off < 16; off <<= 1) {
      #pragma unroll
      for (int rg = 0; rg < 4; ++rg) {
        p0[rg] += __shfl_xor(p0[rg], off);
        p1[rg] += __shfl_xor(p1[rg], off);
      }
    }
    if (arow == 0) {
      #pragma unroll
      for (int rg = 0; rg < 4; ++rg) {
        const int row = t * TROWS + ag * 4 + rg;
        if (row < nrows) {                 // predicate: clamped rows must not double-add
          atomicAdd(&po[row][0], p0[rg]);
          atomicAdd(&po[row][1], p1[rg]);
        }
      }
    }
    __builtin_amdgcn_s_barrier();          // all reads of Xt[cur] done before overwrite
  }

  __syncthreads();

  // fused cumsum + writeout: one thread per batch item
  if (tid < nb) {
    const int gb = (int)lists[e * BS + start + tid];
    float v[NWP * OUT_DIM];
    float s0 = 0.f, s1 = 0.f;
    #pragma unroll
    for (int n = 0; n < NWP; ++n) {
      s0 += po[tid * NWP + n][0];
      s1 += po[tid * NWP + n][1];
      v[n * 2 + 0] = s0;
      v[n * 2 + 1] = s1;
    }
    float4* op = (float4*)(out + (size_t)gb * NWP * OUT_DIM);
    #pragma unroll
    for (int q = 0; q < 5; ++q)
      op[q] = make_float4(v[q * 4], v[q * 4 + 1], v[q * 4 + 2], v[q * 4 + 3]);
  }
}

extern "C" void kernel_launch(void* const* d_in, const int* in_sizes, int n_in,
                              void* d_out, int out_size, void* d_ws, size_t ws_size,
                              hipStream_t stream) {
  const float* x          = (const float*)d_in[0];
  const int*   meas       = (const int*)d_in[1];
  const float* rank_embed = (const float*)d_in[2];
  const float* W1         = (const float*)d_in[3];
  const float* b1         = (const float*)d_in[4];
  const float* W2         = (const float*)d_in[5];
  const float* b2         = (const float*)d_in[6];
  float* out = (float*)d_out;

  int* counts = (int*)d_ws;                                      // 6 ints
  unsigned short* lists = (unsigned short*)((char*)d_ws + 256);  // 6*BS ushort

  hipMemsetAsync(d_ws, 0, 256, stream);
  bucket_k<<<BS / 256, 256, 0, stream>>>(meas, counts, lists);
  dim3 gg((BS + MB - 1) / MB, NEXP);
  moe_gemm_k<<<gg, 256, 0, stream>>>(x, rank_embed, W1, b1, W2, b2,
                                     counts, lists, out);
}

// Round 5
// 171.809 us; speedup vs baseline: 1.5805x; 1.0750x over previous
//
#include <hip/hip_runtime.h>
#include <hip/hip_bf16.h>

#define BS 32768
#define NWP 10
#define DD 256
#define NEXP 6
#define HH 64
#define OUT_DIM 2
#define MB 32
#define TROWS 16
#define NTILE ((MB * NWP) / TROWS)   // 20

typedef short bf16x8 __attribute__((ext_vector_type(8)));
typedef float f32x4 __attribute__((ext_vector_type(4)));

__device__ inline short bfs(float f) {
  __hip_bfloat16 h = __float2bfloat16(f);   // RNE
  return __builtin_bit_cast(short, h);
}

// global -> LDS direct DMA, 16B/lane. Dest wave-uniform base (+lane*16 in HW);
// per-lane SOURCE carries the XOR swizzle (both-sides rule).
__device__ inline void gload_lds16(const float* g, float* l) {
  __builtin_amdgcn_global_load_lds(
      (const __attribute__((address_space(1))) void*)g,
      (__attribute__((address_space(3))) void*)l, 16, 0, 0);
}

// ---------------- kernel 1: bucket batch indices by expert ----------------
__global__ void bucket_k(const int* __restrict__ cmd,
                         int* __restrict__ counts,
                         unsigned short* __restrict__ lists) {
  const int b = blockIdx.x * 256 + threadIdx.x;
  const int e = cmd[b];
  const int lane = threadIdx.x & 63;
  #pragma unroll
  for (int ee = 0; ee < NEXP; ++ee) {
    unsigned long long m = __ballot(e == ee);
    if (e == ee) {
      const int leader = __ffsll((long long)m) - 1;
      const int nbelow = __popcll(m & ((1ull << lane) - 1ull));
      int base = 0;
      if (lane == leader) base = atomicAdd(&counts[ee], __popcll(m));
      base = __shfl(base, leader);
      lists[ee * BS + base + nbelow] = (unsigned short)b;
    }
  }
}

// ---------------- kernel 1b: reW1[e][n][h] = sum_d re[n][d]*W1[e][d][h] ----
__global__ void prep_rew1_k(const float* __restrict__ re,
                            const float* __restrict__ W1,
                            float* __restrict__ reW1) {
  const int e = blockIdx.x;
  for (int i = threadIdx.x; i < NWP * HH; i += 256) {
    const int n = i >> 6, h = i & 63;
    const float* rp = re + (size_t)n * DD;
    const float* wp = W1 + (size_t)e * DD * HH + h;
    float s = 0.f;
    for (int d = 0; d < DD; ++d) s += rp[d] * wp[(size_t)d * HH];
    reW1[((size_t)e * NWP + n) * HH + h] = s;   // fp32, exact
  }
}

// ---------------- kernel 2: pipelined fused GEMM + cumsum ----------------
__global__ __launch_bounds__(256, 3) void moe_gemm_k(
    const float* __restrict__ x,
    const float* __restrict__ W1,
    const float* __restrict__ b1,
    const float* __restrict__ W2,
    const float* __restrict__ b2,
    const float* __restrict__ reW1,
    const int* __restrict__ counts,
    const unsigned short* __restrict__ lists,
    float* __restrict__ out)
{
  __shared__ float Xt[3][TROWS][DD];    // 48 KB triple-buffered x tiles (swizzled)
  __shared__ float rw[NWP][HH + 4];     // 2.72 KB reW1[e], stride 68 (16B-aligned rows)
  __shared__ float po[MB * NWP][2];     // 2.5 KB pre-cumsum outputs

  const int e = blockIdx.y;
  const int cnt = counts[e];
  const int start = blockIdx.x * MB;
  if (start >= cnt) return;
  const int nb = min(MB, cnt - start);
  const int nrows = nb * NWP;

  const int tid = threadIdx.x;
  const int lane = tid & 63;
  const int wv = tid >> 6;
  const int arow = lane & 15;
  const int ag = lane >> 4;

  int bid_reg = 0;
  if (lane < nb) bid_reg = (int)lists[e * BS + start + lane];

  const float bb0 = b2[e * OUT_DIM + 0];
  const float bb1 = b2[e * OUT_DIM + 1];
  for (int i = tid; i < MB * NWP; i += 256) { po[i][0] = bb0; po[i][1] = bb1; }
  for (int i = tid; i < NWP * HH; i += 256)
    rw[i >> 6][i & 63] = reW1[((size_t)e * NWP) * HH + i];

  // A-fragments (registers): lane holds W1T[h = wv*16+arow][k = ks*32+ag*8+j]
  const int hcol = wv * 16 + arow;
  bf16x8 Wf[8];
  {
    const float* wp = W1 + (size_t)e * DD * HH + hcol;
    #pragma unroll
    for (int ks = 0; ks < 8; ++ks)
      #pragma unroll
      for (int j = 0; j < 8; ++j)
        Wf[ks][j] = bfs(wp[(size_t)(ks * 32 + ag * 8 + j) * HH]);
  }
  // epilogue constants for h = wv*16 + ag*4 + rg  (acc row mapping)
  const int hb = wv * 16 + ag * 4;
  const float4 b1v = *(const float4*)(b1 + e * HH + hb);
  const float4 w2a = *(const float4*)(W2 + ((size_t)e * HH + hb) * OUT_DIM);     // h0,h1
  const float4 w2b = *(const float4*)(W2 + ((size_t)e * HH + hb + 2) * OUT_DIM); // h2,h3

  __syncthreads();   // po/rw visible to all; every wave at vmcnt==0

  auto stage = [&](int t, int buf) {
    #pragma unroll
    for (int r = 0; r < 4; ++r) {
      const int rl = wv * 4 + r;
      const int rowc = min(t * TROWS + rl, nrows - 1);
      const int bi = rowc / NWP;
      const int nn = rowc - bi * NWP;
      const int gb = __shfl(bid_reg, bi);   // uniform index, all lanes active
      const float* src = x + ((size_t)gb * NWP + nn) * DD
                       + (((lane * 16) ^ ((rl & 7) << 4)) >> 2);
      gload_lds16(src, &Xt[buf][rl][0]);
    }
  };

  const int key = (arow & 7) << 4;

  auto compute = [&](int t, int buf) {
    const char* xrow = (const char*)&Xt[buf][arow][0];
    f32x4 acc = {0.f, 0.f, 0.f, 0.f};
    #pragma unroll
    for (int ks = 0; ks < 8; ++ks) {
      const int b0 = ks * 128 + ag * 32;
      const float4 xa = *(const float4*)(xrow + (b0 ^ key));
      const float4 xc = *(const float4*)(xrow + ((b0 + 16) ^ key));
      bf16x8 a;
      a[0] = bfs(xa.x); a[1] = bfs(xa.y); a[2] = bfs(xa.z); a[3] = bfs(xa.w);
      a[4] = bfs(xc.x); a[5] = bfs(xc.y); a[6] = bfs(xc.z); a[7] = bfs(xc.w);
      acc = __builtin_amdgcn_mfma_f32_16x16x32_bf16(Wf[ks], a, acc, 0, 0, 0);
    }
    // acc[rg] = S^T[h = hb+rg][batch-row r = t*16+arow]
    const int row = t * TROWS + arow;
    const int rowc = min(row, nrows - 1);
    const int nn = rowc - (rowc / NWP) * NWP;
    const float4 rwv = *(const float4*)&rw[nn][hb];
    const float h0 = fmaxf(acc[0] + b1v.x + rwv.x, 0.f);
    const float h1 = fmaxf(acc[1] + b1v.y + rwv.y, 0.f);
    const float h2 = fmaxf(acc[2] + b1v.z + rwv.z, 0.f);
    const float h3 = fmaxf(acc[3] + b1v.w + rwv.w, 0.f);
    float p0 = h0 * w2a.x + h1 * w2a.z + h2 * w2b.x + h3 * w2b.z;
    float p1 = h0 * w2a.y + h1 * w2a.w + h2 * w2b.y + h3 * w2b.w;
    p0 += __shfl_xor(p0, 16); p1 += __shfl_xor(p1, 16);
    p0 += __shfl_xor(p0, 32); p1 += __shfl_xor(p1, 32);
    if (ag == 0 && row < nrows) {
      atomicAdd(&po[row][0], p0);
      atomicAdd(&po[row][1], p1);
    }
  };

  // depth-2 pipeline: buffers rotate mod 3; steady-state vmcnt(8)
  stage(0, 0);
  stage(1, 1);

  int bc = 0, bn = 1, bp = 2;
  for (int t = 0; t < NTILE - 2; ++t) {
    stage(t + 2, bp);
    asm volatile("s_waitcnt vmcnt(8)" ::: "memory");  // tile t's 4 rows landed
    __builtin_amdgcn_s_barrier();
    __builtin_amdgcn_sched_barrier(0);
    compute(t, bc);
    __builtin_amdgcn_s_barrier();                     // buf bc free for restage
    const int tmp = bc; bc = bn; bn = bp; bp = tmp;
  }
  asm volatile("s_waitcnt vmcnt(4)" ::: "memory");
  __builtin_amdgcn_s_barrier();
  __builtin_amdgcn_sched_barrier(0);
  compute(NTILE - 2, bc);
  __builtin_amdgcn_s_barrier();
  asm volatile("s_waitcnt vmcnt(0)" ::: "memory");
  __builtin_amdgcn_s_barrier();
  __builtin_amdgcn_sched_barrier(0);
  compute(NTILE - 1, bn);

  __syncthreads();   // all po atomics done

  // fused cumsum + writeout: one thread per batch item
  if (tid < nb) {
    const int gb = (int)lists[e * BS + start + tid];
    float v[NWP * OUT_DIM];
    float s0 = 0.f, s1 = 0.f;
    #pragma unroll
    for (int n = 0; n < NWP; ++n) {
      s0 += po[tid * NWP + n][0];
      s1 += po[tid * NWP + n][1];
      v[n * 2 + 0] = s0;
      v[n * 2 + 1] = s1;
    }
    float4* op = (float4*)(out + (size_t)gb * NWP * OUT_DIM);
    #pragma unroll
    for (int q = 0; q < 5; ++q)
      op[q] = make_float4(v[q * 4], v[q * 4 + 1], v[q * 4 + 2], v[q * 4 + 3]);
  }
}

extern "C" void kernel_launch(void* const* d_in, const int* in_sizes, int n_in,
                              void* d_out, int out_size, void* d_ws, size_t ws_size,
                              hipStream_t stream) {
  const float* x          = (const float*)d_in[0];
  const int*   meas       = (const int*)d_in[1];
  const float* rank_embed = (const float*)d_in[2];
  const float* W1         = (const float*)d_in[3];
  const float* b1         = (const float*)d_in[4];
  const float* W2         = (const float*)d_in[5];
  const float* b2         = (const float*)d_in[6];
  float* out = (float*)d_out;

  int* counts = (int*)d_ws;                                      // 6 ints @ 0
  unsigned short* lists = (unsigned short*)((char*)d_ws + 256);  // 6*BS u16
  float* reW1 = (float*)((char*)d_ws + (400 << 10));             // 6*10*64 f32

  hipMemsetAsync(d_ws, 0, 256, stream);
  bucket_k<<<BS / 256, 256, 0, stream>>>(meas, counts, lists);
  prep_rew1_k<<<NEXP, 256, 0, stream>>>(rank_embed, W1, reW1);
  dim3 gg((BS + MB - 1) / MB, NEXP);
  moe_gemm_k<<<gg, 256, 0, stream>>>(x, W1, b1, W2, b2, reW1,
                                     counts, lists, out);
}